// Round 6
// baseline (3444.780 us; speedup 1.0000x reference)
//
#include <hip/hip_runtime.h>
#include <math.h>

#define B_SZ 4096
#define D_SZ 1024
#define H_SZ 1024
#define T_SZ 50

typedef _Float16 f16;
typedef __attribute__((ext_vector_type(8))) _Float16 f16x8;
typedef __attribute__((ext_vector_type(4))) _Float16 f16x4;
typedef __attribute__((ext_vector_type(4))) float f32x4;
typedef __attribute__((ext_vector_type(4))) float f4;

// fast activations: 1 v_exp + 1 v_rcp each; error ~1e-6, far below fp16 noise
__device__ __forceinline__ float fast_sigmoid(float x) {
    return 1.0f / (1.0f + __expf(-x));
}
__device__ __forceinline__ float fast_tanh(float x) {
    return 1.0f - 2.0f / (__expf(2.0f * x) + 1.0f);
}

// async global->LDS, 16 bytes per lane
__device__ __forceinline__ void gl_lds16(const void* g, void* l) {
    __builtin_amdgcn_global_load_lds(
        (const __attribute__((address_space(1))) unsigned int*)g,
        (__attribute__((address_space(3))) unsigned int*)l, 16, 0, 0);
}

// ---------------------------------------------------------------------------
// fp32 -> fp16 conversion (4 elems/thread; n divisible by 4)
__global__ __launch_bounds__(256) void conv_kernel(
        const float* __restrict__ s, f16* __restrict__ d, int n) {
    int i = (blockIdx.x * 256 + threadIdx.x) * 4;
    if (i < n) {
        f4 v = *(const f4*)&s[i];
        f16x4 o = {(f16)v[0], (f16)v[1], (f16)v[2], (f16)v[3]};
        *(f16x4*)&d[i] = o;
    }
}

// ---------------------------------------------------------------------------
// h0 = tanh(ev @ w_init^T + b_init) via fp16 MFMA.
// Tile 128(M) x 64(N), 4 waves 2x2, wave 64x32 (4 mi x 2 ni frags 16x16x32).
__global__ __launch_bounds__(256, 2) void h0_kernel(
        const f16* __restrict__ ev, const f16* __restrict__ wi,
        const float* __restrict__ b_init, f16* __restrict__ hh) {
    __shared__ __align__(16) f16 lds[6144];  // A 128x32 @0, B 64x32 @4096
    const int tid = threadIdx.x;
    const int lane = tid & 63, wave = tid >> 6;
    const int b0 = blockIdx.y * 128, j0 = blockIdx.x * 64;
    const int wm = wave >> 1, wn = wave & 1;
    const int lrow = lane & 15, quad = lane >> 4;

    const f16* gsrc[3];
    int lbase[3];
    {
        const int row16 = lane >> 2, part = lane & 3;
#pragma unroll
        for (int i = 0; i < 3; ++i) {
            int c = wave + 4 * i;
            if (c < 8) {
                gsrc[i] = ev + (size_t)(b0 + c * 16 + row16) * D_SZ + part * 8;
                lbase[i] = c * 512;
            } else {
                int cc = c - 8;
                gsrc[i] = wi + (size_t)(j0 + cc * 16 + row16) * D_SZ + part * 8;
                lbase[i] = 4096 + cc * 512;
            }
        }
    }

    int offA[4], offB[2];
#pragma unroll
    for (int mi = 0; mi < 4; ++mi)
        offA[mi] = (wm * 64 + mi * 16 + lrow) * 32 + quad * 8;
#pragma unroll
    for (int ni = 0; ni < 2; ++ni)
        offB[ni] = 4096 + (wn * 32 + ni * 16 + lrow) * 32 + quad * 8;

    f32x4 acc[4][2] = {};

    for (int k0 = 0; k0 < D_SZ; k0 += 32) {
        __syncthreads();
#pragma unroll
        for (int i = 0; i < 3; ++i)
            gl_lds16(gsrc[i] + k0, &lds[lbase[i]] + lane * 8);
        __syncthreads();
        f16x8 aa[4], bb[2];
#pragma unroll
        for (int mi = 0; mi < 4; ++mi) aa[mi] = *(const f16x8*)&lds[offA[mi]];
#pragma unroll
        for (int ni = 0; ni < 2; ++ni) bb[ni] = *(const f16x8*)&lds[offB[ni]];
#pragma unroll
        for (int mi = 0; mi < 4; ++mi)
#pragma unroll
            for (int ni = 0; ni < 2; ++ni)
                acc[mi][ni] = __builtin_amdgcn_mfma_f32_16x16x32_f16(
                    aa[mi], bb[ni], acc[mi][ni], 0, 0, 0);
    }

#pragma unroll
    for (int ni = 0; ni < 2; ++ni) {
        const int j = j0 + wn * 32 + ni * 16 + lrow;
        const float bj = b_init[j];
#pragma unroll
        for (int mi = 0; mi < 4; ++mi)
#pragma unroll
            for (int reg = 0; reg < 4; ++reg) {
                const int b = b0 + wm * 64 + mi * 16 + quad * 4 + reg;
                hh[(size_t)b * H_SZ + j] = (f16)tanhf(acc[mi][ni][reg] + bj);
            }
    }
}

// ---------------------------------------------------------------------------
// One GRU step: gh = h @ w_hh^T, single-pass fp16 MFMA, double-buffered,
// 512 threads (8 waves) for 4 waves/SIMD at 2 blocks/CU.
// Tile 128(M) x 64(j) x 3 gates; wave grid 2(M) x 4(j): each wave owns
// 64 M x 16 j x 3 gates -> acc[3][4], 12 MFMA + 7 ds_read_b128 per slice.
// LDS: 2 buffers x (A[128][32] 8KB + B[3x64][32] 12KB) = 40 KB.
__global__ __launch_bounds__(512, 4) void step_kernel(
        const f16* __restrict__ hh, const f16* __restrict__ w,
        const float* __restrict__ b_hh, const float* __restrict__ w_ih,
        const float* __restrict__ b_ih, const float* __restrict__ w_out,
        const float* __restrict__ teach, f16* __restrict__ nhh,
        float* __restrict__ out, int t) {
    __shared__ __align__(16) f16 lds[20480];
    const int tid = threadIdx.x;
    const int lane = tid & 63, wave = tid >> 6;  // wave 0..7
    const int b0 = blockIdx.y * 128, j0 = blockIdx.x * 64;
    const int wm = wave >> 2, wn = wave & 3;
    const int lrow = lane & 15, quad = lane >> 4;

    // staging: 20 wave-chunks per BK=32 slice (A 8, B 12); wave takes
    // m = wave, wave+8, wave+16 (skip m>=20).
    const f16* gsrc[3];
    int lbase[3];
    {
        const int r4 = lane >> 2, c4 = lane & 3;
#pragma unroll
        for (int i = 0; i < 3; ++i) {
            int m = wave + 8 * i;
            if (m < 8) {
                gsrc[i] = hh + (size_t)(b0 + m * 16 + r4) * H_SZ + c4 * 8;
                lbase[i] = m * 512 + lane * 8;
            } else if (m < 20) {
                int cb = m - 8;
                int gr = cb * 16 + r4;  // 0..191 = gate*64 + jj
                gsrc[i] = w + (size_t)((gr >> 6) * H_SZ + j0 + (gr & 63)) * H_SZ +
                          c4 * 8;
                lbase[i] = 4096 + cb * 512 + lane * 8;
            } else {
                gsrc[i] = nullptr;
                lbase[i] = 0;
            }
        }
    }

    int offA[4], offB[3];
#pragma unroll
    for (int mi = 0; mi < 4; ++mi)
        offA[mi] = (wm * 64 + mi * 16 + lrow) * 32 + quad * 8;
#pragma unroll
    for (int g = 0; g < 3; ++g)
        offB[g] = 4096 + (g * 64 + wn * 16 + lrow) * 32 + quad * 8;

    f32x4 acc[3][4] = {};

    auto issue = [&](int k, int bufbase) {
#pragma unroll
        for (int i = 0; i < 3; ++i)
            if (wave + 8 * i < 20)
                gl_lds16(gsrc[i] + k * 32, &lds[bufbase + lbase[i]]);
    };
    auto compute = [&](int bufbase) {
        f16x8 aa[4], bb[3];
#pragma unroll
        for (int mi = 0; mi < 4; ++mi)
            aa[mi] = *(const f16x8*)&lds[bufbase + offA[mi]];
#pragma unroll
        for (int g = 0; g < 3; ++g)
            bb[g] = *(const f16x8*)&lds[bufbase + offB[g]];
#pragma unroll
        for (int g = 0; g < 3; ++g)
#pragma unroll
            for (int mi = 0; mi < 4; ++mi)
                acc[g][mi] = __builtin_amdgcn_mfma_f32_16x16x32_f16(
                    aa[mi], bb[g], acc[g][mi], 0, 0, 0);
    };

    issue(0, 0);
    __syncthreads();  // slice 0 landed
    for (int k = 0; k < 32; k += 2) {
        if (k + 1 < 32) issue(k + 1, 10240);
        compute(0);
        __syncthreads();  // slice k+1 landed; buf0 reads done
        if (k + 2 < 32) issue(k + 2, 0);
        compute(10240);
        __syncthreads();  // slice k+2 landed; buf1 reads done
    }

    // -------- fused epilogue: gates, h_next, delta partials --------
    const int j = j0 + wn * 16 + lrow;  // one j per thread
    const float wr0 = w_ih[(0 * H_SZ + j) * 2 + 0];
    const float wr1 = w_ih[(0 * H_SZ + j) * 2 + 1];
    const float wz0 = w_ih[(1 * H_SZ + j) * 2 + 0];
    const float wz1 = w_ih[(1 * H_SZ + j) * 2 + 1];
    const float wn0 = w_ih[(2 * H_SZ + j) * 2 + 0];
    const float wn1 = w_ih[(2 * H_SZ + j) * 2 + 1];
    const float br = b_ih[0 * H_SZ + j] + b_hh[0 * H_SZ + j];
    const float bz = b_ih[1 * H_SZ + j] + b_hh[1 * H_SZ + j];
    const float bn = b_ih[2 * H_SZ + j];
    const float hbn = b_hh[2 * H_SZ + j];
    const float wo0 = w_out[j], wo1 = w_out[H_SZ + j];

#pragma unroll
    for (int mi = 0; mi < 4; ++mi) {
#pragma unroll
        for (int reg = 0; reg < 4; ++reg) {
            const int b = b0 + wm * 64 + mi * 16 + quad * 4 + reg;
            float p0 = 0.f, p1 = 0.f;
            if (t > 0) {
                p0 = teach[b * (T_SZ * 2) + (t - 1) * 2 + 0];
                p1 = teach[b * (T_SZ * 2) + (t - 1) * 2 + 1];
            }
            const float hr = acc[0][mi][reg];
            const float hz = acc[1][mi][reg];
            const float hn_ = acc[2][mi][reg] + hbn;
            const float xr = wr0 * p0 + wr1 * p1 + br;
            const float xz = wz0 * p0 + wz1 * p1 + bz;
            const float xn = wn0 * p0 + wn1 * p1 + bn;
            const float r = fast_sigmoid(xr + hr);
            const float z = fast_sigmoid(xz + hz);
            const float n = fast_tanh(xn + r * hn_);
            const size_t idx = (size_t)b * H_SZ + j;
            const float hold = (float)hh[idx];
            const float hnew = (1.0f - z) * n + z * hold;
            nhh[idx] = (f16)hnew;
            float s0 = hnew * wo0;
            float s1 = hnew * wo1;
#pragma unroll
            for (int m = 1; m < 16; m <<= 1) {
                s0 += __shfl_xor(s0, m);
                s1 += __shfl_xor(s1, m);
            }
            if (lrow == 0) {
                atomicAdd(&out[b * (T_SZ * 2) + t * 2 + 0], s0);
                atomicAdd(&out[b * (T_SZ * 2) + t * 2 + 1], s1);
            }
        }
    }
}

// ---------------------------------------------------------------------------
// pred_deltas += b_out; pred_pos = cumsum
__global__ __launch_bounds__(256) void final_kernel(
        float* __restrict__ out, float* __restrict__ pos,
        const float* __restrict__ b_out) {
    int idx = blockIdx.x * 256 + threadIdx.x;  // b*2 + c
    if (idx >= B_SZ * 2) return;
    int b = idx >> 1, c = idx & 1;
    float bc = b_out[c];
    float acc = 0.0f;
    for (int t = 0; t < T_SZ; ++t) {
        float d = out[b * (T_SZ * 2) + t * 2 + c] + bc;
        out[b * (T_SZ * 2) + t * 2 + c] = d;
        acc += d;
        pos[b * (T_SZ * 2) + t * 2 + c] = acc;
    }
}

// ---------------------------------------------------------------------------
extern "C" void kernel_launch(void* const* d_in, const int* in_sizes, int n_in,
                              void* d_out, int out_size, void* d_ws, size_t ws_size,
                              hipStream_t stream) {
    const float* ev     = (const float*)d_in[0];
    const float* teach  = (const float*)d_in[1];
    const float* w_init = (const float*)d_in[2];
    const float* b_init = (const float*)d_in[3];
    const float* w_ih   = (const float*)d_in[4];
    const float* w_hh   = (const float*)d_in[5];
    const float* b_ih   = (const float*)d_in[6];
    const float* b_hh   = (const float*)d_in[7];
    const float* w_out  = (const float*)d_in[8];
    const float* b_out  = (const float*)d_in[9];

    float* out = (float*)d_out;                  // pred_deltas (B,T,2)
    float* pos = out + (size_t)B_SZ * T_SZ * 2;  // pred_pos    (B,T,2)

    // ws layout (f16 units): hA (4M), hB (4M), w_hh (3M), w_init (1M).
    // ev_f16 (4M) aliases hB (consumed by h0 before hB is first written).
    f16* ws = (f16*)d_ws;
    f16* hA    = ws;
    f16* hB    = hA + (size_t)B_SZ * H_SZ;
    f16* whh   = hB + (size_t)B_SZ * H_SZ;
    f16* winit = whh + (size_t)3 * H_SZ * H_SZ;
    f16* evf   = hB;  // alias

    hipMemsetAsync(out, 0, (size_t)B_SZ * T_SZ * 2 * sizeof(float), stream);

    conv_kernel<<<(3 * H_SZ * H_SZ) / 1024, 256, 0, stream>>>(w_hh, whh, 3 * H_SZ * H_SZ);
    conv_kernel<<<(H_SZ * D_SZ) / 1024, 256, 0, stream>>>(w_init, winit, H_SZ * D_SZ);
    conv_kernel<<<(B_SZ * D_SZ) / 1024, 256, 0, stream>>>(ev, evf, B_SZ * D_SZ);

    dim3 grid(H_SZ / 64, B_SZ / 128);  // (16, 32) = 512 blocks
    h0_kernel<<<grid, 256, 0, stream>>>(evf, winit, b_init, hA);

    f16 *hc = hA, *hn = hB;
    for (int t = 0; t < T_SZ; ++t) {
        step_kernel<<<grid, 512, 0, stream>>>(hc, whh, b_hh, w_ih, b_ih, w_out,
                                              teach, hn, out, t);
        f16* tmp = hc; hc = hn; hn = tmp;
    }
    final_kernel<<<(B_SZ * 2 + 255) / 256, 256, 0, stream>>>(out, pos, b_out);
}

// Round 7
// 2417.322 us; speedup vs baseline: 1.4250x; 1.4250x over previous
//
#include <hip/hip_runtime.h>
#include <math.h>

#define B_SZ 4096
#define D_SZ 1024
#define H_SZ 1024
#define T_SZ 50

typedef _Float16 f16;
typedef __attribute__((ext_vector_type(8))) _Float16 f16x8;
typedef __attribute__((ext_vector_type(4))) _Float16 f16x4;
typedef __attribute__((ext_vector_type(4))) float f32x4;
typedef __attribute__((ext_vector_type(4))) float f4;

// fast activations: 1 v_exp + 1 v_rcp each; error ~1e-6, far below fp16 noise
__device__ __forceinline__ float fast_sigmoid(float x) {
    return 1.0f / (1.0f + __expf(-x));
}
__device__ __forceinline__ float fast_tanh(float x) {
    return 1.0f - 2.0f / (__expf(2.0f * x) + 1.0f);
}

// async global->LDS, 16 bytes per lane
__device__ __forceinline__ void gl_lds16(const void* g, void* l) {
    __builtin_amdgcn_global_load_lds(
        (const __attribute__((address_space(1))) unsigned int*)g,
        (__attribute__((address_space(3))) unsigned int*)l, 16, 0, 0);
}

// ---------------------------------------------------------------------------
// fp32 -> fp16 conversion (4 elems/thread; n divisible by 4)
__global__ __launch_bounds__(256) void conv_kernel(
        const float* __restrict__ s, f16* __restrict__ d, int n) {
    int i = (blockIdx.x * 256 + threadIdx.x) * 4;
    if (i < n) {
        f4 v = *(const f4*)&s[i];
        f16x4 o = {(f16)v[0], (f16)v[1], (f16)v[2], (f16)v[3]};
        *(f16x4*)&d[i] = o;
    }
}

// ---------------------------------------------------------------------------
// h0 = tanh(ev @ w_init^T + b_init) via fp16 MFMA.
// Tile 128(M) x 64(N), 4 waves 2x2, wave 64x32 (4 mi x 2 ni frags 16x16x32).
__global__ __launch_bounds__(256, 2) void h0_kernel(
        const f16* __restrict__ ev, const f16* __restrict__ wi,
        const float* __restrict__ b_init, f16* __restrict__ hh) {
    __shared__ __align__(16) f16 lds[6144];  // A 128x32 @0, B 64x32 @4096
    const int tid = threadIdx.x;
    const int lane = tid & 63, wave = tid >> 6;
    const int b0 = blockIdx.y * 128, j0 = blockIdx.x * 64;
    const int wm = wave >> 1, wn = wave & 1;
    const int lrow = lane & 15, quad = lane >> 4;

    const f16* gsrc[3];
    int lbase[3];
    {
        const int row16 = lane >> 2, part = lane & 3;
#pragma unroll
        for (int i = 0; i < 3; ++i) {
            int c = wave + 4 * i;
            if (c < 8) {
                gsrc[i] = ev + (size_t)(b0 + c * 16 + row16) * D_SZ + part * 8;
                lbase[i] = c * 512;
            } else {
                int cc = c - 8;
                gsrc[i] = wi + (size_t)(j0 + cc * 16 + row16) * D_SZ + part * 8;
                lbase[i] = 4096 + cc * 512;
            }
        }
    }

    int offA[4], offB[2];
#pragma unroll
    for (int mi = 0; mi < 4; ++mi)
        offA[mi] = (wm * 64 + mi * 16 + lrow) * 32 + quad * 8;
#pragma unroll
    for (int ni = 0; ni < 2; ++ni)
        offB[ni] = 4096 + (wn * 32 + ni * 16 + lrow) * 32 + quad * 8;

    f32x4 acc[4][2] = {};

    for (int k0 = 0; k0 < D_SZ; k0 += 32) {
        __syncthreads();
#pragma unroll
        for (int i = 0; i < 3; ++i)
            gl_lds16(gsrc[i] + k0, &lds[lbase[i]] + lane * 8);
        __syncthreads();
        f16x8 aa[4], bb[2];
#pragma unroll
        for (int mi = 0; mi < 4; ++mi) aa[mi] = *(const f16x8*)&lds[offA[mi]];
#pragma unroll
        for (int ni = 0; ni < 2; ++ni) bb[ni] = *(const f16x8*)&lds[offB[ni]];
#pragma unroll
        for (int mi = 0; mi < 4; ++mi)
#pragma unroll
            for (int ni = 0; ni < 2; ++ni)
                acc[mi][ni] = __builtin_amdgcn_mfma_f32_16x16x32_f16(
                    aa[mi], bb[ni], acc[mi][ni], 0, 0, 0);
    }

#pragma unroll
    for (int ni = 0; ni < 2; ++ni) {
        const int j = j0 + wn * 32 + ni * 16 + lrow;
        const float bj = b_init[j];
#pragma unroll
        for (int mi = 0; mi < 4; ++mi)
#pragma unroll
            for (int reg = 0; reg < 4; ++reg) {
                const int b = b0 + wm * 64 + mi * 16 + quad * 4 + reg;
                hh[(size_t)b * H_SZ + j] = (f16)tanhf(acc[mi][ni][reg] + bj);
            }
    }
}

// ---------------------------------------------------------------------------
// One GRU step: gh = h @ w_hh^T, single-pass fp16 MFMA, double-buffered.
// 128 threads = 2 FAT waves; tile 64(M) x 64(j) x 3 gates; wave tile
// 32M x (64j x 3g) = 24 MFMA + 14 ds_read_b128 per BK=32 slice.
// LDS: 2 x (A[64][32] 4KB + B[192][32] 12KB) = 32 KB -> 4 blocks/CU:
// 4 INDEPENDENT 2-wave barrier groups per CU (vs R5's 2x4 — finer overlap).
__global__ __launch_bounds__(128, 2) void step_kernel(
        const f16* __restrict__ hh, const f16* __restrict__ w,
        const float* __restrict__ b_hh, const float* __restrict__ w_ih,
        const float* __restrict__ b_ih, const float* __restrict__ w_out,
        const float* __restrict__ teach, f16* __restrict__ nhh,
        float* __restrict__ out, int t) {
    __shared__ __align__(16) f16 lds[16384];  // 2 x 8192-elem buffers
    const int tid = threadIdx.x;
    const int lane = tid & 63, wave = tid >> 6;  // wave = wm (0,1)
    const int b0 = blockIdx.y * 64, j0 = blockIdx.x * 64;
    const int lrow = lane & 15, quad = lane >> 4;

    // staging: 16 chunks (A 4, B 12) x 512 elems; 8 wave-issues per wave.
    const f16* gsrc[8];
    int lbase[8];
    {
        const int r4 = lane >> 2, c4 = lane & 3;
#pragma unroll
        for (int i = 0; i < 8; ++i) {
            int m = wave + 2 * i;
            if (m < 4) {
                gsrc[i] = hh + (size_t)(b0 + m * 16 + r4) * H_SZ + c4 * 8;
                lbase[i] = m * 512 + lane * 8;
            } else {
                int cb = m - 4;
                int gr = cb * 16 + r4;  // 0..191 = gate*64 + jj
                gsrc[i] = w + (size_t)((gr >> 6) * H_SZ + j0 + (gr & 63)) * H_SZ +
                          c4 * 8;
                lbase[i] = 2048 + cb * 512 + lane * 8;
            }
        }
    }

    int offA[2], offB[3][4];
#pragma unroll
    for (int mi = 0; mi < 2; ++mi)
        offA[mi] = (wave * 32 + mi * 16 + lrow) * 32 + quad * 8;
#pragma unroll
    for (int g = 0; g < 3; ++g)
#pragma unroll
        for (int ni = 0; ni < 4; ++ni)
            offB[g][ni] = 2048 + (g * 64 + ni * 16 + lrow) * 32 + quad * 8;

    f32x4 acc[3][2][4] = {};

    auto issue = [&](int k, int bufbase) {
#pragma unroll
        for (int i = 0; i < 8; ++i)
            gl_lds16(gsrc[i] + k * 32, &lds[bufbase + lbase[i]]);
    };
    auto compute = [&](int bufbase) {
        f16x8 aa[2];
#pragma unroll
        for (int mi = 0; mi < 2; ++mi)
            aa[mi] = *(const f16x8*)&lds[bufbase + offA[mi]];
#pragma unroll
        for (int g = 0; g < 3; ++g) {
#pragma unroll
            for (int ni = 0; ni < 4; ++ni) {
                f16x8 bb = *(const f16x8*)&lds[bufbase + offB[g][ni]];
#pragma unroll
                for (int mi = 0; mi < 2; ++mi)
                    acc[g][mi][ni] = __builtin_amdgcn_mfma_f32_16x16x32_f16(
                        aa[mi], bb, acc[g][mi][ni], 0, 0, 0);
            }
        }
    };

    issue(0, 0);
    __syncthreads();  // slice 0 landed
    for (int k = 0; k < 32; k += 2) {
        if (k + 1 < 32) issue(k + 1, 8192);
        compute(0);
        __syncthreads();  // slice k+1 landed; buf0 reads done
        if (k + 2 < 32) issue(k + 2, 0);
        compute(8192);
        __syncthreads();  // slice k+2 landed; buf1 reads done
    }

    // -------- fused epilogue: gates, h_next, delta partials --------
    float p0[2][4], p1[2][4];
#pragma unroll
    for (int mi = 0; mi < 2; ++mi)
#pragma unroll
        for (int reg = 0; reg < 4; ++reg) {
            const int b = b0 + wave * 32 + mi * 16 + quad * 4 + reg;
            if (t > 0) {
                p0[mi][reg] = teach[b * (T_SZ * 2) + (t - 1) * 2 + 0];
                p1[mi][reg] = teach[b * (T_SZ * 2) + (t - 1) * 2 + 1];
            } else {
                p0[mi][reg] = 0.f;
                p1[mi][reg] = 0.f;
            }
        }

    float s0[2][4] = {}, s1[2][4] = {};
#pragma unroll
    for (int ni = 0; ni < 4; ++ni) {
        const int j = j0 + ni * 16 + lrow;
        const float wr0 = w_ih[(0 * H_SZ + j) * 2 + 0];
        const float wr1 = w_ih[(0 * H_SZ + j) * 2 + 1];
        const float wz0 = w_ih[(1 * H_SZ + j) * 2 + 0];
        const float wz1 = w_ih[(1 * H_SZ + j) * 2 + 1];
        const float wn0 = w_ih[(2 * H_SZ + j) * 2 + 0];
        const float wn1 = w_ih[(2 * H_SZ + j) * 2 + 1];
        const float br = b_ih[0 * H_SZ + j] + b_hh[0 * H_SZ + j];
        const float bz = b_ih[1 * H_SZ + j] + b_hh[1 * H_SZ + j];
        const float bn = b_ih[2 * H_SZ + j];
        const float hbn = b_hh[2 * H_SZ + j];
        const float wo0 = w_out[j], wo1 = w_out[H_SZ + j];
#pragma unroll
        for (int mi = 0; mi < 2; ++mi) {
#pragma unroll
            for (int reg = 0; reg < 4; ++reg) {
                const int b = b0 + wave * 32 + mi * 16 + quad * 4 + reg;
                const float hr = acc[0][mi][ni][reg];
                const float hz = acc[1][mi][ni][reg];
                const float hn_ = acc[2][mi][ni][reg] + hbn;
                const float xr = wr0 * p0[mi][reg] + wr1 * p1[mi][reg] + br;
                const float xz = wz0 * p0[mi][reg] + wz1 * p1[mi][reg] + bz;
                const float xn = wn0 * p0[mi][reg] + wn1 * p1[mi][reg] + bn;
                const float r = fast_sigmoid(xr + hr);
                const float z = fast_sigmoid(xz + hz);
                const float n = fast_tanh(xn + r * hn_);
                const size_t idx = (size_t)b * H_SZ + j;
                const float hold = (float)hh[idx];
                const float hnew = (1.0f - z) * n + z * hold;
                nhh[idx] = (f16)hnew;
                s0[mi][reg] += hnew * wo0;
                s1[mi][reg] += hnew * wo1;
            }
        }
    }
#pragma unroll
    for (int mi = 0; mi < 2; ++mi)
#pragma unroll
        for (int reg = 0; reg < 4; ++reg) {
            float a = s0[mi][reg], c = s1[mi][reg];
#pragma unroll
            for (int m = 1; m < 16; m <<= 1) {
                a += __shfl_xor(a, m);
                c += __shfl_xor(c, m);
            }
            if (lrow == 0) {
                const int b = b0 + wave * 32 + mi * 16 + quad * 4 + reg;
                atomicAdd(&out[b * (T_SZ * 2) + t * 2 + 0], a);
                atomicAdd(&out[b * (T_SZ * 2) + t * 2 + 1], c);
            }
        }
}

// ---------------------------------------------------------------------------
// pred_deltas += b_out; pred_pos = cumsum
__global__ __launch_bounds__(256) void final_kernel(
        float* __restrict__ out, float* __restrict__ pos,
        const float* __restrict__ b_out) {
    int idx = blockIdx.x * 256 + threadIdx.x;  // b*2 + c
    if (idx >= B_SZ * 2) return;
    int b = idx >> 1, c = idx & 1;
    float bc = b_out[c];
    float acc = 0.0f;
    for (int t = 0; t < T_SZ; ++t) {
        float d = out[b * (T_SZ * 2) + t * 2 + c] + bc;
        out[b * (T_SZ * 2) + t * 2 + c] = d;
        acc += d;
        pos[b * (T_SZ * 2) + t * 2 + c] = acc;
    }
}

// ---------------------------------------------------------------------------
extern "C" void kernel_launch(void* const* d_in, const int* in_sizes, int n_in,
                              void* d_out, int out_size, void* d_ws, size_t ws_size,
                              hipStream_t stream) {
    const float* ev     = (const float*)d_in[0];
    const float* teach  = (const float*)d_in[1];
    const float* w_init = (const float*)d_in[2];
    const float* b_init = (const float*)d_in[3];
    const float* w_ih   = (const float*)d_in[4];
    const float* w_hh   = (const float*)d_in[5];
    const float* b_ih   = (const float*)d_in[6];
    const float* b_hh   = (const float*)d_in[7];
    const float* w_out  = (const float*)d_in[8];
    const float* b_out  = (const float*)d_in[9];

    float* out = (float*)d_out;                  // pred_deltas (B,T,2)
    float* pos = out + (size_t)B_SZ * T_SZ * 2;  // pred_pos    (B,T,2)

    // ws layout (f16 units): hA (4M), hB (4M), w_hh (3M), w_init (1M).
    // ev_f16 (4M) aliases hB (consumed by h0 before hB is first written).
    f16* ws = (f16*)d_ws;
    f16* hA    = ws;
    f16* hB    = hA + (size_t)B_SZ * H_SZ;
    f16* whh   = hB + (size_t)B_SZ * H_SZ;
    f16* winit = whh + (size_t)3 * H_SZ * H_SZ;
    f16* evf   = hB;  // alias

    hipMemsetAsync(out, 0, (size_t)B_SZ * T_SZ * 2 * sizeof(float), stream);

    conv_kernel<<<(3 * H_SZ * H_SZ) / 1024, 256, 0, stream>>>(w_hh, whh, 3 * H_SZ * H_SZ);
    conv_kernel<<<(H_SZ * D_SZ) / 1024, 256, 0, stream>>>(w_init, winit, H_SZ * D_SZ);
    conv_kernel<<<(B_SZ * D_SZ) / 1024, 256, 0, stream>>>(ev, evf, B_SZ * D_SZ);

    dim3 g0(H_SZ / 64, B_SZ / 128);  // (16, 32)
    h0_kernel<<<g0, 256, 0, stream>>>(evf, winit, b_init, hA);

    dim3 gs(H_SZ / 64, B_SZ / 64);  // (16, 64) = 1024 blocks = 4 blocks/CU
    f16 *hc = hA, *hn = hB;
    for (int t = 0; t < T_SZ; ++t) {
        step_kernel<<<gs, 128, 0, stream>>>(hc, whh, b_hh, w_ih, b_ih, w_out,
                                            teach, hn, out, t);
        f16* tmp = hc; hc = hn; hn = tmp;
    }
    final_kernel<<<(B_SZ * 2 + 255) / 256, 256, 0, stream>>>(out, pos, b_out);
}